// Round 1
// baseline (66.479 us; speedup 1.0000x reference)
//
#include <hip/hip_runtime.h>
#include <hip/hip_bf16.h>

// Problem constants (fixed by reference setup_inputs)
#define BB 4
#define LL 4096
#define MM 1024
#define DD 2048
#define SEG 8
#define SM 128   // MM / SEG

// ---------------------------------------------------------------------------
// Kernel A: per-batch prep.
//  - block-wide cumsum of boundary_mask over L=4096 (1024 thr x 4 elems)
//  - scatter clipped p into p_chunked (stable partition: boundary first)
//  - chunk_idx[b,l] = clip(incl_cumsum-1, 0, M-1)
//  - P[b,t] = in-segment inclusive prefix product of a[t] (a[0]=0, else 1-p)
// ---------------------------------------------------------------------------
__global__ __launch_bounds__(1024) void prep_kernel(
    const float* __restrict__ bprob,   // (B, L, 2)
    const int*   __restrict__ bmask,   // (B, L) 0/1
    float* __restrict__ p_chunked,     // (B, M)
    int*   __restrict__ chunk_idx,     // (B, L)
    float* __restrict__ Ppref)         // (B, M)
{
    const int b   = blockIdx.x;
    const int tid = threadIdx.x;
    const int lane = tid & 63;
    const int wid  = tid >> 6;

    __shared__ int   wsum[16];
    __shared__ int   s_total;
    __shared__ float wprod[16];

    // ---- load 4 mask values per thread (contiguous int4) ----
    int4 mv = reinterpret_cast<const int4*>(bmask + b * LL)[tid];
    int ms[4] = { mv.x, mv.y, mv.z, mv.w };
    int s = ms[0] + ms[1] + ms[2] + ms[3];

    // wave inclusive scan of per-thread sums
    int v = s;
    #pragma unroll
    for (int off = 1; off < 64; off <<= 1) {
        int u = __shfl_up(v, off, 64);
        if (lane >= off) v += u;
    }
    if (lane == 63) wsum[wid] = v;
    __syncthreads();
    if (tid == 0) {
        int acc = 0;
        #pragma unroll
        for (int w = 0; w < 16; ++w) { int t = wsum[w]; wsum[w] = acc; acc += t; }
        s_total = acc;
    }
    __syncthreads();

    const int NB = s_total;                 // total boundary tokens in batch
    int e = (v - s) + wsum[wid];            // exclusive prefix for first elem

    const int base_l = tid * 4;
    #pragma unroll
    for (int j = 0; j < 4; ++j) {
        int l = base_l + j;
        int m = ms[j];
        int incl = e + m;
        int ci = incl - 1;
        ci = ci < 0 ? 0 : (ci > MM - 1 ? MM - 1 : ci);
        chunk_idx[b * LL + l] = ci;
        int pos = m ? e : (NB + (l - e));   // stable partition position
        if (pos < MM) {
            float p = bprob[((size_t)b * LL + l) * 2 + 1];
            p = fminf(fmaxf(p, 1e-4f), 1.0f - 1e-4f);
            p_chunked[b * MM + pos] = p;
        }
        e = incl;
    }
    __syncthreads();

    // ---- in-segment prefix products: t = tid (M = 1024 = blockDim) ----
    {
        int t = tid;
        float p = p_chunked[b * MM + t];
        float a = (t == 0) ? 0.0f : (1.0f - p);
        float pr = a;
        #pragma unroll
        for (int off = 1; off < 64; off <<= 1) {
            float u = __shfl_up(pr, off, 64);
            if (lane >= off) pr *= u;
        }
        if (lane == 63) wprod[wid] = pr;
        __syncthreads();
        float P = pr;
        // segment = 128 elems = 2 waves; odd wave multiplies by even wave total
        if (wid & 1) P *= wprod[wid - 1];
        Ppref[b * MM + t] = P;
    }
}

// ---------------------------------------------------------------------------
// Kernel B: segmented local EMA scan (zero initial carry per segment).
// grid = (D/256, SEG, B), block = 256. One thread per d-channel.
// ---------------------------------------------------------------------------
__global__ __launch_bounds__(256) void scan_kernel(
    const float* __restrict__ x,          // (B, M, D)
    const float* __restrict__ p_chunked,  // (B, M)
    float* __restrict__ local)            // (B, M, D)
{
    const int d   = blockIdx.x * 256 + threadIdx.x;
    const int seg = blockIdx.y;
    const int b   = blockIdx.z;
    const float* pc = p_chunked + b * MM;
    const int t0 = seg * SM;
    size_t base = ((size_t)b * MM + t0) * DD + d;

    float prev = 0.0f;
    #pragma unroll 4
    for (int i = 0; i < SM; ++i) {
        int t = t0 + i;
        float p  = pc[t];
        float xt = x[base + (size_t)i * DD];
        float a, bt;
        if (t == 0) { a = 0.0f; bt = xt; }
        else        { a = 1.0f - p; bt = p * xt; }
        prev = fmaf(a, prev, bt);
        local[base + (size_t)i * DD] = prev;
    }
}

// ---------------------------------------------------------------------------
// Kernel C: combine carries across the 8 segments, per (b,d).
// carry[b,seg,d] = true y at last element of segment seg-1 (0 for seg 0).
// ---------------------------------------------------------------------------
__global__ __launch_bounds__(256) void carry_kernel(
    const float* __restrict__ local,
    const float* __restrict__ Ppref,
    float* __restrict__ carry)            // (B, SEG, D)
{
    int idx = blockIdx.x * 256 + threadIdx.x;   // over B*D
    int b = idx >> 11;                           // / 2048
    int d = idx & (DD - 1);
    size_t lbase = (size_t)b * MM * DD + d;
    float run = 0.0f;
    #pragma unroll
    for (int s = 0; s < SEG; ++s) {
        carry[((size_t)b * SEG + s) * DD + d] = run;
        float last = local[lbase + (size_t)(s * SM + SM - 1) * DD];
        float Pf   = Ppref[b * MM + s * SM + SM - 1];
        run = fmaf(Pf, run, last);
    }
}

// ---------------------------------------------------------------------------
// Kernel D: gather + carry fix-up fused.
// out[b,l,:] = local[b,t,:] + P[b,t] * carry[b,seg(t),:],  t = chunk_idx[b,l]
// grid = (L, B), block = 256, float4 (512 float4 per row -> 2 per thread).
// ---------------------------------------------------------------------------
__global__ __launch_bounds__(256) void gather_kernel(
    const float* __restrict__ local,
    const float* __restrict__ Ppref,
    const float* __restrict__ carry,
    const int*   __restrict__ chunk_idx,
    float* __restrict__ out)              // (B, L, D)
{
    const int l = blockIdx.x;
    const int b = blockIdx.y;
    const int t = chunk_idx[b * LL + l];
    const float Pt = Ppref[b * MM + t];
    const int seg = t >> 7;

    const float4* lrow = reinterpret_cast<const float4*>(local + ((size_t)b * MM + t) * DD);
    const float4* crow = reinterpret_cast<const float4*>(carry + ((size_t)b * SEG + seg) * DD);
    float4* orow       = reinterpret_cast<float4*>(out + ((size_t)b * LL + l) * DD);

    const int tid = threadIdx.x;
    #pragma unroll
    for (int k = 0; k < 2; ++k) {
        int i = tid + k * 256;            // 512 float4 per row
        float4 lv = lrow[i];
        float4 cv = crow[i];
        float4 ov;
        ov.x = fmaf(Pt, cv.x, lv.x);
        ov.y = fmaf(Pt, cv.y, lv.y);
        ov.z = fmaf(Pt, cv.z, lv.z);
        ov.w = fmaf(Pt, cv.w, lv.w);
        orow[i] = ov;
    }
}

// ---------------------------------------------------------------------------
extern "C" void kernel_launch(void* const* d_in, const int* in_sizes, int n_in,
                              void* d_out, int out_size, void* d_ws, size_t ws_size,
                              hipStream_t stream) {
    const float* x     = (const float*)d_in[0];   // chunked_states (B,M,D) f32
    const float* bprob = (const float*)d_in[1];   // boundary_prob  (B,L,2) f32
    const int*   bmask = (const int*)d_in[2];     // boundary_mask  (B,L) int
    float* out = (float*)d_out;

    // workspace layout
    float* local     = (float*)d_ws;                       // B*M*D floats
    float* p_chunked = local + (size_t)BB * MM * DD;       // B*M
    float* Ppref     = p_chunked + BB * MM;                // B*M
    float* carry     = Ppref + BB * MM;                    // B*SEG*D
    int*   chunk_idx = (int*)(carry + (size_t)BB * SEG * DD); // B*L ints

    prep_kernel<<<BB, 1024, 0, stream>>>(bprob, bmask, p_chunked, chunk_idx, Ppref);
    scan_kernel<<<dim3(DD / 256, SEG, BB), 256, 0, stream>>>(x, p_chunked, local);
    carry_kernel<<<(BB * DD) / 256, 256, 0, stream>>>(local, Ppref, carry);
    gather_kernel<<<dim3(LL, BB), 256, 0, stream>>>(local, Ppref, carry, chunk_idx, out);
}

// Round 3
// 59.426 us; speedup vs baseline: 1.1187x; 1.1187x over previous
//
#include <hip/hip_runtime.h>
#include <hip/hip_bf16.h>

// Problem constants (fixed by reference setup_inputs)
#define BB 4
#define LL 4096
#define MM 1024
#define DD 2048
#define SEG 32
#define SM 32          // MM / SEG
#define SEGSHIFT 5

typedef float f32x4 __attribute__((ext_vector_type(4)));

// ---------------------------------------------------------------------------
// Kernel A: per-batch prep.
//  - block-wide cumsum of boundary_mask over L=4096 (1024 thr x 4 elems)
//  - scatter clipped p into p_chunked (stable partition: boundary first)
//  - chunk_idx[b,l] = clip(incl_cumsum-1, 0, M-1)
//  - Ppref[b,t] = in-segment (32-wide) inclusive prefix product of a[t]
//    where a[0]=0, a[t]=1-p[t]
// ---------------------------------------------------------------------------
__global__ __launch_bounds__(1024) void prep_kernel(
    const float* __restrict__ bprob,   // (B, L, 2)
    const int*   __restrict__ bmask,   // (B, L) 0/1
    float* __restrict__ p_chunked,     // (B, M)
    int*   __restrict__ chunk_idx,     // (B, L)
    float* __restrict__ Ppref)         // (B, M)
{
    const int b   = blockIdx.x;
    const int tid = threadIdx.x;
    const int lane = tid & 63;
    const int wid  = tid >> 6;

    __shared__ int wsum[16];
    __shared__ int s_total;

    // ---- load 4 mask values per thread (contiguous int4) ----
    int4 mv = reinterpret_cast<const int4*>(bmask + b * LL)[tid];
    int ms[4] = { mv.x, mv.y, mv.z, mv.w };
    int s = ms[0] + ms[1] + ms[2] + ms[3];

    // wave inclusive scan of per-thread sums
    int v = s;
    #pragma unroll
    for (int off = 1; off < 64; off <<= 1) {
        int u = __shfl_up(v, off, 64);
        if (lane >= off) v += u;
    }
    if (lane == 63) wsum[wid] = v;
    __syncthreads();
    if (tid == 0) {
        int acc = 0;
        #pragma unroll
        for (int w = 0; w < 16; ++w) { int t = wsum[w]; wsum[w] = acc; acc += t; }
        s_total = acc;
    }
    __syncthreads();

    const int NB = s_total;                 // total boundary tokens in batch
    int e = (v - s) + wsum[wid];            // exclusive prefix for first elem

    const int base_l = tid * 4;
    #pragma unroll
    for (int j = 0; j < 4; ++j) {
        int l = base_l + j;
        int m = ms[j];
        int incl = e + m;
        int ci = incl - 1;
        ci = ci < 0 ? 0 : (ci > MM - 1 ? MM - 1 : ci);
        chunk_idx[b * LL + l] = ci;
        int pos = m ? e : (NB + (l - e));   // stable partition position
        if (pos < MM) {
            float p = bprob[((size_t)b * LL + l) * 2 + 1];
            p = fminf(fmaxf(p, 1e-4f), 1.0f - 1e-4f);
            p_chunked[b * MM + pos] = p;
        }
        e = incl;
    }
    __syncthreads();

    // ---- in-segment prefix products over 32-wide segments: t = tid ----
    {
        int t = tid;
        float p = p_chunked[b * MM + t];
        float a = (t == 0) ? 0.0f : (1.0f - p);
        float pr = a;
        #pragma unroll
        for (int off = 1; off < 32; off <<= 1) {
            float u = __shfl_up(pr, off, 32);   // within 32-wide subgroups
            if ((tid & 31) >= off) pr *= u;
        }
        Ppref[b * MM + t] = pr;
    }
}

// ---------------------------------------------------------------------------
// Kernel B: segmented local EMA scan (zero initial carry per segment).
// grid = (D/512, SEG, B) = (4, 32, 4) = 512 blocks, block = 256.
// One thread handles 2 consecutive d-channels (float2).
// Also emits compact seglast[b,seg,d] = local value at segment end.
// ---------------------------------------------------------------------------
__global__ __launch_bounds__(256) void scan_kernel(
    const float* __restrict__ x,          // (B, M, D)
    const float* __restrict__ p_chunked,  // (B, M)
    float* __restrict__ local,            // (B, M, D)
    float* __restrict__ seglast)          // (B, SEG, D)
{
    const int d0  = blockIdx.x * 512 + threadIdx.x * 2;
    const int seg = blockIdx.y;
    const int b   = blockIdx.z;
    const int t0  = seg * SM;

    __shared__ float sp[SM];
    if (threadIdx.x < SM) sp[threadIdx.x] = p_chunked[b * MM + t0 + threadIdx.x];
    __syncthreads();

    size_t base = ((size_t)b * MM + t0) * DD + d0;

    float2 prev = make_float2(0.0f, 0.0f);
    #pragma unroll
    for (int i = 0; i < SM; ++i) {
        float p = sp[i];
        bool first = (seg == 0) && (i == 0);
        float ac = first ? 0.0f : (1.0f - p);
        float bc = first ? 1.0f : p;
        float2 xt = *reinterpret_cast<const float2*>(x + base + (size_t)i * DD);
        prev.x = fmaf(ac, prev.x, bc * xt.x);
        prev.y = fmaf(ac, prev.y, bc * xt.y);
        *reinterpret_cast<float2*>(local + base + (size_t)i * DD) = prev;
    }
    *reinterpret_cast<float2*>(seglast + ((size_t)b * SEG + seg) * DD + d0) = prev;
}

// ---------------------------------------------------------------------------
// Kernel C: combine carries across the 32 segments, per (b,d).
// carry[b,seg,d] = true y at last element of segment seg-1 (0 for seg 0).
// Reads only the compact seglast buffer (L2-resident).
// ---------------------------------------------------------------------------
__global__ __launch_bounds__(256) void carry_kernel(
    const float* __restrict__ seglast,    // (B, SEG, D)
    const float* __restrict__ Ppref,      // (B, M)
    float* __restrict__ carry)            // (B, SEG, D)
{
    int idx = blockIdx.x * 256 + threadIdx.x;   // over B*D
    int b = idx >> 11;                           // / 2048
    int d = idx & (DD - 1);

    // prefetch all segment-last values and segment products
    float lastv[SEG];
    #pragma unroll
    for (int s = 0; s < SEG; ++s)
        lastv[s] = seglast[((size_t)b * SEG + s) * DD + d];

    float run = 0.0f;
    #pragma unroll
    for (int s = 0; s < SEG; ++s) {
        carry[((size_t)b * SEG + s) * DD + d] = run;
        float Pf = Ppref[b * MM + s * SM + SM - 1];   // uniform scalar load
        run = fmaf(Pf, run, lastv[s]);
    }
}

// ---------------------------------------------------------------------------
// Kernel D: gather + carry fix-up fused.
// out[b,l,:] = local[b,t,:] + P[b,t] * carry[b,seg(t),:],  t = chunk_idx[b,l]
// grid = (L, B), block = 256, f32x4 (512 vec4 per row -> 2 per thread).
// Non-temporal stores: out is write-once; keep local rows in L2/LLC.
// ---------------------------------------------------------------------------
__global__ __launch_bounds__(256) void gather_kernel(
    const float* __restrict__ local,
    const float* __restrict__ Ppref,
    const float* __restrict__ carry,
    const int*   __restrict__ chunk_idx,
    float* __restrict__ out)              // (B, L, D)
{
    const int l = blockIdx.x;
    const int b = blockIdx.y;
    const int t = chunk_idx[b * LL + l];
    const float Pt = Ppref[b * MM + t];
    const int seg = t >> SEGSHIFT;

    const f32x4* lrow = reinterpret_cast<const f32x4*>(local + ((size_t)b * MM + t) * DD);
    const f32x4* crow = reinterpret_cast<const f32x4*>(carry + ((size_t)b * SEG + seg) * DD);
    f32x4* orow       = reinterpret_cast<f32x4*>(out + ((size_t)b * LL + l) * DD);

    const int tid = threadIdx.x;
    #pragma unroll
    for (int k = 0; k < 2; ++k) {
        int i = tid + k * 256;            // 512 vec4 per row
        f32x4 lv = lrow[i];
        f32x4 cv = crow[i];
        f32x4 ov = lv + Pt * cv;
        __builtin_nontemporal_store(ov, &orow[i]);
    }
}

// ---------------------------------------------------------------------------
extern "C" void kernel_launch(void* const* d_in, const int* in_sizes, int n_in,
                              void* d_out, int out_size, void* d_ws, size_t ws_size,
                              hipStream_t stream) {
    const float* x     = (const float*)d_in[0];   // chunked_states (B,M,D) f32
    const float* bprob = (const float*)d_in[1];   // boundary_prob  (B,L,2) f32
    const int*   bmask = (const int*)d_in[2];     // boundary_mask  (B,L) int

    float* out = (float*)d_out;

    // workspace layout
    float* local     = (float*)d_ws;                          // B*M*D
    float* p_chunked = local + (size_t)BB * MM * DD;          // B*M
    float* Ppref     = p_chunked + BB * MM;                   // B*M
    float* carry     = Ppref + BB * MM;                       // B*SEG*D
    float* seglast   = carry + (size_t)BB * SEG * DD;         // B*SEG*D
    int*   chunk_idx = (int*)(seglast + (size_t)BB * SEG * DD); // B*L

    prep_kernel<<<BB, 1024, 0, stream>>>(bprob, bmask, p_chunked, chunk_idx, Ppref);
    scan_kernel<<<dim3(DD / 512, SEG, BB), 256, 0, stream>>>(x, p_chunked, local, seglast);
    carry_kernel<<<(BB * DD) / 256, 256, 0, stream>>>(seglast, Ppref, carry);
    gather_kernel<<<dim3(LL, BB), 256, 0, stream>>>(local, Ppref, carry, chunk_idx, out);
}